// Round 5
// baseline (156.220 us; speedup 1.0000x reference)
//
#include <hip/hip_runtime.h>
#include <math.h>

constexpr int DIM   = 128;
constexpr int KC    = 1024;
constexpr int NROWS = 65536;                 // 16384*512/128
constexpr int XEL   = NROWS * DIM;           // 8388608

// output layout (floats)
constexpr int OUT_Z     = 0;
constexpr int OUT_DIFF  = XEL;               // 8388608
constexpr int OUT_CODES = XEL + 1;           // 8388609
constexpr int OUT_PPL   = XEL + 1 + NROWS;   // 8454145

// ws layout (4-byte units)
constexpr int WS_IDX  = 0;                   // int[NROWS]
constexpr int WS_FLAG = NROWS;               // int[NROWS]
constexpr int WS_CNT  = 2 * NROWS;           // int   (zeroed by k_prep)
constexpr int WS_DONE = WS_CNT + 1;          // u32   (zeroed by k_prep)
constexpr int WS_HIST = WS_DONE + 1;         // u32[KC] (zeroed by k_prep)
constexpr int WS_HN   = WS_HIST + KC;        // float[KC]
constexpr int WS_PART = WS_HN + KC;          // float[2048] diff partials
constexpr int WS_EF   = WS_PART + 2048;      // _Float16[KC*DIM] = 65536 words

constexpr int NB_OUT = 2048;                 // k_output blocks

// single-pass f16 score error std ~4e-3; 0.06 = >10 sigma pairwise margin
constexpr float GAP_THR = 0.06f;

typedef _Float16 f16x8 __attribute__((ext_vector_type(8)));
typedef _Float16 f16x4 __attribute__((ext_vector_type(4)));
typedef float f32x4 __attribute__((ext_vector_type(4)));

// ---- emb -> f16, fp64-exact half-norms, zero counters/hist ----
__global__ __launch_bounds__(256) void k_prep(
        const float* __restrict__ emb, _Float16* __restrict__ ef,
        float* __restrict__ hn, unsigned* __restrict__ zbase) {
    const int tid = threadIdx.x;
    if (blockIdx.x == 0)
        for (int i = tid; i < 2 + KC; i += 256) zbase[i] = 0u;   // CNT, DONE, HIST
    const int code = blockIdx.x * 8 + (tid >> 5);
    const int j0 = (tid & 31) * 4;
    float4 v = *(const float4*)(emb + (size_t)code * DIM + j0);
    f16x4 h = { (_Float16)v.x, (_Float16)v.y, (_Float16)v.z, (_Float16)v.w };
    *(f16x4*)(ef + (size_t)code * DIM + j0) = h;
    double s = (double)v.x * v.x + (double)v.y * v.y
             + (double)v.z * v.z + (double)v.w * v.w;
    #pragma unroll
    for (int m = 1; m < 32; m <<= 1) s += __shfl_xor(s, m);
    if ((tid & 31) == 0) hn[code] = (float)(0.5 * s);
}

// ---- main: single-pass f16 MFMA scores, 64 rows/wave, top-2 + argmax ----
__global__ __launch_bounds__(128) void k_argmin(
        const float* __restrict__ x, const _Float16* __restrict__ ef,
        const float* __restrict__ hn, int* __restrict__ idx_out,
        int* __restrict__ flag_cnt, int* __restrict__ flagged) {
    __shared__ _Float16 lds[4096];            // 8 KB: 8 chunks of 1 KB
    const int tid = threadIdx.x;
    const int l = tid & 63, w = tid >> 6;     // 2 waves
    const int lr = l & 15, lg = l >> 4;
    const int r0 = blockIdx.x * 128 + w * 64; // 64 rows per wave

    // A fragments: 64 rows as f16 (4 row-groups x 4 k-tiles), in registers
    f16x8 a[4][4];
    #pragma unroll
    for (int i = 0; i < 4; ++i) {
        const float* xr = x + (size_t)(r0 + i * 16 + lr) * DIM + lg * 8;
        #pragma unroll
        for (int kt = 0; kt < 4; ++kt) {
            float4 v0 = *(const float4*)(xr + kt * 32);
            float4 v1 = *(const float4*)(xr + kt * 32 + 4);
            f16x8 av = { (_Float16)v0.x, (_Float16)v0.y, (_Float16)v0.z, (_Float16)v0.w,
                         (_Float16)v1.x, (_Float16)v1.y, (_Float16)v1.z, (_Float16)v1.w };
            a[i][kt] = av;
        }
    }

    // staging: 8 chunks/tile (c in 0..1, kt in 0..3), wave w stages q=w*4+i
    const _Float16* esrc[4];
    #pragma unroll
    for (int i = 0; i < 4; ++i) {
        int q = w * 4 + i, c = q >> 2, kt = q & 3;
        esrc[i] = ef + (size_t)(c * 16 + lr) * DIM + kt * 32 + lg * 8;
    }
    f16x8 st[4];
    #pragma unroll
    for (int i = 0; i < 4; ++i) st[i] = *(const f16x8*)(esrc[i]);

    float m1[4][4], m2[4][4]; int bi[4][4];
    #pragma unroll
    for (int i = 0; i < 4; ++i)
        #pragma unroll
        for (int rg = 0; rg < 4; ++rg) { m1[i][rg] = -3e38f; m2[i][rg] = -3e38f; bi[i][rg] = 0; }

    for (int t = 0; t < KC / 32; ++t) {
        __syncthreads();                      // prev tile's readers done
        #pragma unroll
        for (int i = 0; i < 4; ++i)
            *(f16x8*)(lds + (w * 4 + i) * 512 + l * 8) = st[i];
        __syncthreads();                      // tile t visible
        if (t < KC / 32 - 1) {
            #pragma unroll
            for (int i = 0; i < 4; ++i) st[i] = *(const f16x8*)(esrc[i] + (t + 1) * 32 * DIM);
        }
        const float h0 = hn[t * 32 + lr], h1 = hn[t * 32 + 16 + lr];
        f32x4 acc[4][2];
        #pragma unroll
        for (int i = 0; i < 4; ++i) {
            acc[i][0] = (f32x4){-h0, -h0, -h0, -h0};
            acc[i][1] = (f32x4){-h1, -h1, -h1, -h1};
        }
        #pragma unroll
        for (int kt = 0; kt < 4; ++kt) {
            f16x8 b0 = *(const f16x8*)(lds + kt * 512 + l * 8);
            f16x8 b1 = *(const f16x8*)(lds + 2048 + kt * 512 + l * 8);
            #pragma unroll
            for (int i = 0; i < 4; ++i) {
                acc[i][0] = __builtin_amdgcn_mfma_f32_16x16x32_f16(a[i][kt], b0, acc[i][0], 0, 0, 0);
                acc[i][1] = __builtin_amdgcn_mfma_f32_16x16x32_f16(a[i][kt], b1, acc[i][1], 0, 0, 0);
            }
        }
        const int c0 = t * 32 + lr, c1 = c0 + 16;
        #pragma unroll
        for (int i = 0; i < 4; ++i)
            #pragma unroll
            for (int rg = 0; rg < 4; ++rg) {
                float v0 = acc[i][0][rg], v1 = acc[i][1][rg];
                bool g0 = v0 > m1[i][rg];
                m2[i][rg] = fmaxf(m2[i][rg], fminf(v0, m1[i][rg]));
                m1[i][rg] = fmaxf(m1[i][rg], v0);
                bi[i][rg] = g0 ? c0 : bi[i][rg];
                bool g1 = v1 > m1[i][rg];
                m2[i][rg] = fmaxf(m2[i][rg], fminf(v1, m1[i][rg]));
                m1[i][rg] = fmaxf(m1[i][rg], v1);
                bi[i][rg] = g1 ? c1 : bi[i][rg];
            }
    }

    // merge top-2 across the 16 lanes sharing each row
    #pragma unroll
    for (int i = 0; i < 4; ++i)
        #pragma unroll
        for (int rg = 0; rg < 4; ++rg) {
            float a1 = m1[i][rg], a2 = m2[i][rg]; int ai = bi[i][rg];
            #pragma unroll
            for (int mask = 1; mask < 16; mask <<= 1) {
                float o1 = __shfl_xor(a1, mask);
                float o2 = __shfl_xor(a2, mask);
                int   oi = __shfl_xor(ai, mask);
                float nm2 = fmaxf(fmaxf(a2, o2), fminf(a1, o1));
                if (o1 > a1 || (o1 == a1 && oi < ai)) { a1 = o1; ai = oi; }
                a2 = nm2;
            }
            if (lr == 0) {
                int row = r0 + i * 16 + lg * 4 + rg;
                idx_out[row] = ai;
                if (a1 - a2 < GAP_THR) {      // near-tie: exact recheck later
                    int p = atomicAdd(flag_cnt, 1);
                    flagged[p] = row;
                }
            }
        }
}

// ---- exact fp64 recheck: one block per flagged row, thread per code ----
__global__ __launch_bounds__(256) void k_recheck(
        const float* __restrict__ x, const float* __restrict__ emb,
        int* __restrict__ idx_out, const int* __restrict__ flag_cnt,
        const int* __restrict__ flagged) {
    __shared__ float xs[DIM];
    __shared__ double wv[4];
    __shared__ int    wk[4];
    const int tid = threadIdx.x;
    const int cnt = flag_cnt[0];
    for (int f = blockIdx.x; f < cnt; f += gridDim.x) {
        const int row = flagged[f];
        __syncthreads();                       // xs/wv reuse guard
        if (tid < DIM) xs[tid] = x[(size_t)row * DIM + tid];
        __syncthreads();
        double bv = -1e300; int bk = 0;
        #pragma unroll
        for (int tile = 0; tile < 4; ++tile) {
            const int k = tile * 256 + tid;
            const float4* ep = (const float4*)(emb + (size_t)k * DIM);
            const float4* xp = (const float4*)xs;
            double s = 0.0, n2 = 0.0;
            #pragma unroll 8
            for (int jq = 0; jq < DIM / 4; ++jq) {
                float4 ev = ep[jq];
                float4 xv = xp[jq];
                double e0 = ev.x, e1 = ev.y, e2 = ev.z, e3 = ev.w;
                s  = fma(e0, (double)xv.x, s);  n2 = fma(e0, e0, n2);
                s  = fma(e1, (double)xv.y, s);  n2 = fma(e1, e1, n2);
                s  = fma(e2, (double)xv.z, s);  n2 = fma(e2, e2, n2);
                s  = fma(e3, (double)xv.w, s);  n2 = fma(e3, e3, n2);
            }
            s -= 0.5 * n2;
            if (s > bv) { bv = s; bk = k; }   // ascending k keeps first-min
        }
        #pragma unroll
        for (int m = 1; m < 64; m <<= 1) {
            double ov = __shfl_xor(bv, m);
            int    ok = __shfl_xor(bk, m);
            if (ov > bv || (ov == bv && ok < bk)) { bv = ov; bk = ok; }
        }
        const int w = tid >> 6;
        if ((tid & 63) == 0) { wv[w] = bv; wk[w] = bk; }
        __syncthreads();
        if (tid == 0) {
            double fv = wv[0]; int fk = wk[0];
            #pragma unroll
            for (int i = 1; i < 4; ++i)
                if (wv[i] > fv || (wv[i] == fv && wk[i] < fk)) { fv = wv[i]; fk = wk[i]; }
            idx_out[row] = fk;
        }
    }
}

// ---- z, codes, diff partials (no global atomics) ----
__global__ __launch_bounds__(256) void k_output(
        const float* __restrict__ x, const float* __restrict__ emb,
        const int* __restrict__ idx, float* __restrict__ out,
        float* __restrict__ part) {
    const int tid = threadIdx.x;
    float d = 0.f;
    #pragma unroll
    for (int it = 0; it < 4; ++it) {
        int i = blockIdx.x * 256 + tid + it * (NB_OUT * 256);
        int e0 = i * 4;
        int row = e0 >> 7;
        int col = e0 & (DIM - 1);
        int k = idx[row];
        float4 xv = *(const float4*)(x + e0);
        float4 qv = *(const float4*)(emb + (size_t)k * DIM + col);
        float dx = qv.x - xv.x, dy = qv.y - xv.y, dz = qv.z - xv.z, dw = qv.w - xv.w;
        float4 z;
        z.x = xv.x + dx; z.y = xv.y + dy; z.z = xv.z + dz; z.w = xv.w + dw;
        *(float4*)(out + OUT_Z + e0) = z;
        d += dx*dx + dy*dy + dz*dz + dw*dw;
        if (col == 0) out[OUT_CODES + row] = (float)k;
    }
    for (int off = 32; off; off >>= 1) d += __shfl_down(d, off);
    __shared__ float red[4];
    int lane = tid & 63, w = tid >> 6;
    if (lane == 0) red[w] = d;
    __syncthreads();
    if (tid == 0) part[blockIdx.x] = (red[0] + red[1]) + (red[2] + red[3]);
}

// ---- histogram (64 blocks) + finalize in last-done block ----
__global__ __launch_bounds__(256) void k_hist(
        const int* __restrict__ idx, unsigned* __restrict__ ghist,
        const float* __restrict__ part, unsigned* __restrict__ done,
        float* __restrict__ out) {
    __shared__ unsigned hist[KC];
    __shared__ double sh[256];
    __shared__ unsigned rank_sh;
    const int tid = threadIdx.x;
    #pragma unroll
    for (int i = 0; i < KC / 256; ++i) hist[i * 256 + tid] = 0u;
    __syncthreads();
    const int base = blockIdx.x * (NROWS / 64);
    #pragma unroll
    for (int it = 0; it < NROWS / 64 / 256; ++it)
        atomicAdd(&hist[idx[base + it * 256 + tid]], 1u);
    __syncthreads();
    #pragma unroll
    for (int i = 0; i < KC / 256; ++i) {
        unsigned c = hist[i * 256 + tid];
        if (c) atomicAdd(&ghist[i * 256 + tid], c);
    }
    __syncthreads();                          // all this block's merges complete
    if (tid == 0) { __threadfence(); rank_sh = atomicAdd(done, 1u); }
    __syncthreads();
    if (rank_sh != 63) return;
    // last block: diff mean + perplexity
    double s = 0.0;
    #pragma unroll
    for (int it = 0; it < 2048 / 256; ++it) s += (double)part[it * 256 + tid];
    sh[tid] = s;
    __syncthreads();
    for (int st = 128; st; st >>= 1) {
        if (tid < st) sh[tid] += sh[tid + st];
        __syncthreads();
    }
    double diff = sh[0] * (1.0 / (double)XEL);
    double lp = 0.0;
    #pragma unroll
    for (int i = 0; i < KC / 256; ++i) {
        unsigned c = atomicAdd(&ghist[i * 256 + tid], 0u);   // coherent read
        double p = (double)c * (1.0 / (double)NROWS);
        lp += p * log(p + 1e-5);
    }
    __syncthreads();
    sh[tid] = lp;
    __syncthreads();
    for (int st = 128; st; st >>= 1) {
        if (tid < st) sh[tid] += sh[tid + st];
        __syncthreads();
    }
    if (tid == 0) {
        out[OUT_DIFF] = (float)diff;
        out[OUT_PPL]  = (float)(-sh[0]);
    }
}

extern "C" void kernel_launch(void* const* d_in, const int* in_sizes, int n_in,
                              void* d_out, int out_size, void* d_ws, size_t ws_size,
                              hipStream_t stream) {
    const float* x   = (const float*)d_in[0];
    const float* emb = (const float*)d_in[1];
    float* out = (float*)d_out;
    int*   wi  = (int*)d_ws;
    float* wf  = (float*)d_ws;
    unsigned* wu = (unsigned*)d_ws;
    _Float16* ef = (_Float16*)((float*)d_ws + WS_EF);

    k_prep<<<KC / 8, 256, 0, stream>>>(emb, ef, wf + WS_HN, wu + WS_CNT);
    k_argmin<<<NROWS / 128, 128, 0, stream>>>(x, ef, wf + WS_HN,
                                              wi + WS_IDX, wi + WS_CNT, wi + WS_FLAG);
    k_recheck<<<1024, 256, 0, stream>>>(x, emb, wi + WS_IDX, wi + WS_CNT, wi + WS_FLAG);
    k_output<<<NB_OUT, 256, 0, stream>>>(x, emb, wi + WS_IDX, out, wf + WS_PART);
    k_hist<<<64, 256, 0, stream>>>(wi + WS_IDX, wu + WS_HIST, wf + WS_PART,
                                   wu + WS_DONE, out);
}

// Round 6
// 109.761 us; speedup vs baseline: 1.4233x; 1.4233x over previous
//
#include <hip/hip_runtime.h>
#include <math.h>

constexpr int DIM   = 128;
constexpr int KC    = 1024;
constexpr int NROWS = 65536;                 // 16384*512/128
constexpr int XEL   = NROWS * DIM;           // 8388608

// output layout (floats)
constexpr int OUT_Z     = 0;
constexpr int OUT_DIFF  = XEL;               // 8388608
constexpr int OUT_CODES = XEL + 1;           // 8388609
constexpr int OUT_PPL   = XEL + 1 + NROWS;   // 8454145

// ws layout (4-byte units)
constexpr int WS_IDX  = 0;                   // int[NROWS]
constexpr int WS_FLAG = NROWS;               // int[NROWS]
constexpr int WS_CNT  = 2 * NROWS;           // int   (zeroed by k_prep)
constexpr int WS_DONE = WS_CNT + 1;          // u32   (zeroed by k_prep)
constexpr int WS_HIST = WS_DONE + 1;         // u32[KC] (zeroed by k_prep)
constexpr int WS_HN   = WS_HIST + KC;        // float[KC]
constexpr int WS_PART = WS_HN + KC;          // float[2048] diff partials
constexpr int WS_HN64 = WS_PART + 2048;      // double[KC] (2048 words, 8B-aligned)
constexpr int WS_EF   = WS_HN64 + 2 * KC;    // _Float16[KC*DIM] = 65536 words
constexpr int WS_ET   = WS_EF + (KC * DIM / 2); // float[DIM*KC] transposed = 131072 words

constexpr int NB_OUT = 2048;                 // k_output blocks

// single-pass f16 score error std ~5e-3; 0.06 = >10 sigma pairwise margin
constexpr float GAP_THR = 0.06f;

typedef _Float16 f16x8 __attribute__((ext_vector_type(8)));
typedef _Float16 f16x4 __attribute__((ext_vector_type(4)));
typedef float f32x4 __attribute__((ext_vector_type(4)));

// ---- emb -> f16 + transposed fp32 + fp64 half-norms; zero counters/hist ----
__global__ __launch_bounds__(256) void k_prep(
        const float* __restrict__ emb, _Float16* __restrict__ ef,
        float* __restrict__ embT, float* __restrict__ hn,
        double* __restrict__ hn64, unsigned* __restrict__ zbase) {
    __shared__ float ldsT[DIM][9];            // 8 codes transposed, +1 pad col
    const int tid = threadIdx.x;
    if (blockIdx.x == 0)
        for (int i = tid; i < 2 + KC; i += 256) zbase[i] = 0u;   // CNT, DONE, HIST
    const int cc   = tid >> 5;                // 0..7 code within block
    const int code = blockIdx.x * 8 + cc;
    const int jq   = tid & 31;                // float4 index
    float4 v = *(const float4*)(emb + (size_t)code * DIM + jq * 4);
    f16x4 h = { (_Float16)v.x, (_Float16)v.y, (_Float16)v.z, (_Float16)v.w };
    *(f16x4*)(ef + (size_t)code * DIM + jq * 4) = h;
    ldsT[jq * 4 + 0][cc] = v.x;
    ldsT[jq * 4 + 1][cc] = v.y;
    ldsT[jq * 4 + 2][cc] = v.z;
    ldsT[jq * 4 + 3][cc] = v.w;
    double s = (double)v.x * v.x + (double)v.y * v.y
             + (double)v.z * v.z + (double)v.w * v.w;
    #pragma unroll
    for (int m = 1; m < 32; m <<= 1) s += __shfl_xor(s, m);
    if (jq == 0) {
        hn[code]   = (float)(0.5 * s);
        hn64[code] = 0.5 * s;
    }
    __syncthreads();
    #pragma unroll
    for (int i = 0; i < 4; ++i) {
        int idx = i * 256 + tid;
        int j = idx >> 3, c = idx & 7;
        embT[(size_t)j * KC + blockIdx.x * 8 + c] = ldsT[j][c];
    }
}

// ---- main: single-pass f16 MFMA scores, 64 rows/wave, top-2 + argmax ----
__global__ __launch_bounds__(128) void k_argmin(
        const float* __restrict__ x, const _Float16* __restrict__ ef,
        const float* __restrict__ hn, int* __restrict__ idx_out,
        int* __restrict__ flag_cnt, int* __restrict__ flagged) {
    __shared__ _Float16 lds[4096];            // 8 KB: 8 chunks of 1 KB
    const int tid = threadIdx.x;
    const int l = tid & 63, w = tid >> 6;     // 2 waves
    const int lr = l & 15, lg = l >> 4;
    const int r0 = blockIdx.x * 128 + w * 64; // 64 rows per wave

    // A fragments: 64 rows as f16 (4 row-groups x 4 k-tiles), in registers
    f16x8 a[4][4];
    #pragma unroll
    for (int i = 0; i < 4; ++i) {
        const float* xr = x + (size_t)(r0 + i * 16 + lr) * DIM + lg * 8;
        #pragma unroll
        for (int kt = 0; kt < 4; ++kt) {
            float4 v0 = *(const float4*)(xr + kt * 32);
            float4 v1 = *(const float4*)(xr + kt * 32 + 4);
            f16x8 av = { (_Float16)v0.x, (_Float16)v0.y, (_Float16)v0.z, (_Float16)v0.w,
                         (_Float16)v1.x, (_Float16)v1.y, (_Float16)v1.z, (_Float16)v1.w };
            a[i][kt] = av;
        }
    }

    // staging: 8 chunks/tile (c in 0..1, kt in 0..3), wave w stages q=w*4+i
    const _Float16* esrc[4];
    #pragma unroll
    for (int i = 0; i < 4; ++i) {
        int q = w * 4 + i, c = q >> 2, kt = q & 3;
        esrc[i] = ef + (size_t)(c * 16 + lr) * DIM + kt * 32 + lg * 8;
    }
    f16x8 st[4];
    #pragma unroll
    for (int i = 0; i < 4; ++i) st[i] = *(const f16x8*)(esrc[i]);

    float m1[4][4], m2[4][4]; int bi[4][4];
    #pragma unroll
    for (int i = 0; i < 4; ++i)
        #pragma unroll
        for (int rg = 0; rg < 4; ++rg) { m1[i][rg] = -3e38f; m2[i][rg] = -3e38f; bi[i][rg] = 0; }

    for (int t = 0; t < KC / 32; ++t) {
        __syncthreads();                      // prev tile's readers done
        #pragma unroll
        for (int i = 0; i < 4; ++i)
            *(f16x8*)(lds + (w * 4 + i) * 512 + l * 8) = st[i];
        __syncthreads();                      // tile t visible
        if (t < KC / 32 - 1) {
            #pragma unroll
            for (int i = 0; i < 4; ++i) st[i] = *(const f16x8*)(esrc[i] + (t + 1) * 32 * DIM);
        }
        const float h0 = hn[t * 32 + lr], h1 = hn[t * 32 + 16 + lr];
        f32x4 acc[4][2];
        #pragma unroll
        for (int i = 0; i < 4; ++i) {
            acc[i][0] = (f32x4){-h0, -h0, -h0, -h0};
            acc[i][1] = (f32x4){-h1, -h1, -h1, -h1};
        }
        #pragma unroll
        for (int kt = 0; kt < 4; ++kt) {
            f16x8 b0 = *(const f16x8*)(lds + kt * 512 + l * 8);
            f16x8 b1 = *(const f16x8*)(lds + 2048 + kt * 512 + l * 8);
            #pragma unroll
            for (int i = 0; i < 4; ++i) {
                acc[i][0] = __builtin_amdgcn_mfma_f32_16x16x32_f16(a[i][kt], b0, acc[i][0], 0, 0, 0);
                acc[i][1] = __builtin_amdgcn_mfma_f32_16x16x32_f16(a[i][kt], b1, acc[i][1], 0, 0, 0);
            }
        }
        const int c0 = t * 32 + lr, c1 = c0 + 16;
        #pragma unroll
        for (int i = 0; i < 4; ++i)
            #pragma unroll
            for (int rg = 0; rg < 4; ++rg) {
                float v0 = acc[i][0][rg], v1 = acc[i][1][rg];
                bool g0 = v0 > m1[i][rg];
                m2[i][rg] = fmaxf(m2[i][rg], fminf(v0, m1[i][rg]));
                m1[i][rg] = fmaxf(m1[i][rg], v0);
                bi[i][rg] = g0 ? c0 : bi[i][rg];
                bool g1 = v1 > m1[i][rg];
                m2[i][rg] = fmaxf(m2[i][rg], fminf(v1, m1[i][rg]));
                m1[i][rg] = fmaxf(m1[i][rg], v1);
                bi[i][rg] = g1 ? c1 : bi[i][rg];
            }
    }

    // merge top-2 across the 16 lanes sharing each row
    #pragma unroll
    for (int i = 0; i < 4; ++i)
        #pragma unroll
        for (int rg = 0; rg < 4; ++rg) {
            float a1 = m1[i][rg], a2 = m2[i][rg]; int ai = bi[i][rg];
            #pragma unroll
            for (int mask = 1; mask < 16; mask <<= 1) {
                float o1 = __shfl_xor(a1, mask);
                float o2 = __shfl_xor(a2, mask);
                int   oi = __shfl_xor(ai, mask);
                float nm2 = fmaxf(fmaxf(a2, o2), fminf(a1, o1));
                if (o1 > a1 || (o1 == a1 && oi < ai)) { a1 = o1; ai = oi; }
                a2 = nm2;
            }
            if (lr == 0) {
                int row = r0 + i * 16 + lg * 4 + rg;
                idx_out[row] = ai;
                if (a1 - a2 < GAP_THR) {      // near-tie: exact recheck later
                    int p = atomicAdd(flag_cnt, 1);
                    flagged[p] = row;
                }
            }
        }
}

// ---- exact fp64 recheck over transposed codebook: block per flagged row ----
// thread t owns codes {t, t+256, t+512, t+768}; wave reads 64 consecutive
// floats of embT per step -> fully coalesced, L2-resident.
__global__ __launch_bounds__(256) void k_recheck(
        const float* __restrict__ x, const float* __restrict__ embT,
        const double* __restrict__ hn64, int* __restrict__ idx_out,
        const int* __restrict__ flag_cnt, const int* __restrict__ flagged) {
    __shared__ double xd[DIM];
    __shared__ double wv[4];
    __shared__ int    wk[4];
    const int tid = threadIdx.x;
    const int cnt = flag_cnt[0];
    for (int f = blockIdx.x; f < cnt; f += gridDim.x) {
        const int row = flagged[f];
        __syncthreads();                       // xd/wv reuse guard
        if (tid < DIM) xd[tid] = (double)x[(size_t)row * DIM + tid];
        __syncthreads();
        const float* tp = embT + tid;
        double s0 = 0.0, s1 = 0.0, s2 = 0.0, s3 = 0.0;
        #pragma unroll 4
        for (int j = 0; j < DIM; ++j) {
            const float* rp = tp + (size_t)j * KC;
            double xv = xd[j];
            s0 = fma((double)rp[0],   xv, s0);
            s1 = fma((double)rp[256], xv, s1);
            s2 = fma((double)rp[512], xv, s2);
            s3 = fma((double)rp[768], xv, s3);
        }
        double bv = s0 - hn64[tid];       int bk = tid;
        double v1 = s1 - hn64[tid + 256];
        if (v1 > bv) { bv = v1; bk = tid + 256; }
        double v2 = s2 - hn64[tid + 512];
        if (v2 > bv) { bv = v2; bk = tid + 512; }
        double v3 = s3 - hn64[tid + 768];
        if (v3 > bv) { bv = v3; bk = tid + 768; }
        #pragma unroll
        for (int m = 1; m < 64; m <<= 1) {
            double ov = __shfl_xor(bv, m);
            int    ok = __shfl_xor(bk, m);
            if (ov > bv || (ov == bv && ok < bk)) { bv = ov; bk = ok; }
        }
        const int w = tid >> 6;
        if ((tid & 63) == 0) { wv[w] = bv; wk[w] = bk; }
        __syncthreads();
        if (tid == 0) {
            double fv = wv[0]; int fk = wk[0];
            #pragma unroll
            for (int i = 1; i < 4; ++i)
                if (wv[i] > fv || (wv[i] == fv && wk[i] < fk)) { fv = wv[i]; fk = wk[i]; }
            idx_out[row] = fk;
        }
    }
}

// ---- z, codes, diff partials (no global atomics) ----
__global__ __launch_bounds__(256) void k_output(
        const float* __restrict__ x, const float* __restrict__ emb,
        const int* __restrict__ idx, float* __restrict__ out,
        float* __restrict__ part) {
    const int tid = threadIdx.x;
    float d = 0.f;
    #pragma unroll
    for (int it = 0; it < 4; ++it) {
        int i = blockIdx.x * 256 + tid + it * (NB_OUT * 256);
        int e0 = i * 4;
        int row = e0 >> 7;
        int col = e0 & (DIM - 1);
        int k = idx[row];
        float4 xv = *(const float4*)(x + e0);
        float4 qv = *(const float4*)(emb + (size_t)k * DIM + col);
        float dx = qv.x - xv.x, dy = qv.y - xv.y, dz = qv.z - xv.z, dw = qv.w - xv.w;
        float4 z;
        z.x = xv.x + dx; z.y = xv.y + dy; z.z = xv.z + dz; z.w = xv.w + dw;
        *(float4*)(out + OUT_Z + e0) = z;
        d += dx*dx + dy*dy + dz*dz + dw*dw;
        if (col == 0) out[OUT_CODES + row] = (float)k;
    }
    for (int off = 32; off; off >>= 1) d += __shfl_down(d, off);
    __shared__ float red[4];
    int lane = tid & 63, w = tid >> 6;
    if (lane == 0) red[w] = d;
    __syncthreads();
    if (tid == 0) part[blockIdx.x] = (red[0] + red[1]) + (red[2] + red[3]);
}

// ---- histogram (64 blocks) + finalize in last-done block ----
__global__ __launch_bounds__(256) void k_hist(
        const int* __restrict__ idx, unsigned* __restrict__ ghist,
        const float* __restrict__ part, unsigned* __restrict__ done,
        float* __restrict__ out) {
    __shared__ unsigned hist[KC];
    __shared__ double sh[256];
    __shared__ unsigned rank_sh;
    const int tid = threadIdx.x;
    #pragma unroll
    for (int i = 0; i < KC / 256; ++i) hist[i * 256 + tid] = 0u;
    __syncthreads();
    const int base = blockIdx.x * (NROWS / 64);
    #pragma unroll
    for (int it = 0; it < NROWS / 64 / 256; ++it)
        atomicAdd(&hist[idx[base + it * 256 + tid]], 1u);
    __syncthreads();
    #pragma unroll
    for (int i = 0; i < KC / 256; ++i) {
        unsigned c = hist[i * 256 + tid];
        if (c) atomicAdd(&ghist[i * 256 + tid], c);
    }
    __syncthreads();                          // all this block's merges complete
    if (tid == 0) { __threadfence(); rank_sh = atomicAdd(done, 1u); }
    __syncthreads();
    if (rank_sh != 63) return;
    // last block: diff mean + perplexity
    double s = 0.0;
    #pragma unroll
    for (int it = 0; it < 2048 / 256; ++it) s += (double)part[it * 256 + tid];
    sh[tid] = s;
    __syncthreads();
    for (int st = 128; st; st >>= 1) {
        if (tid < st) sh[tid] += sh[tid + st];
        __syncthreads();
    }
    double diff = sh[0] * (1.0 / (double)XEL);
    double lp = 0.0;
    #pragma unroll
    for (int i = 0; i < KC / 256; ++i) {
        unsigned c = atomicAdd(&ghist[i * 256 + tid], 0u);   // coherent read
        double p = (double)c * (1.0 / (double)NROWS);
        lp += p * log(p + 1e-5);
    }
    __syncthreads();
    sh[tid] = lp;
    __syncthreads();
    for (int st = 128; st; st >>= 1) {
        if (tid < st) sh[tid] += sh[tid + st];
        __syncthreads();
    }
    if (tid == 0) {
        out[OUT_DIFF] = (float)diff;
        out[OUT_PPL]  = (float)(-sh[0]);
    }
}

extern "C" void kernel_launch(void* const* d_in, const int* in_sizes, int n_in,
                              void* d_out, int out_size, void* d_ws, size_t ws_size,
                              hipStream_t stream) {
    const float* x   = (const float*)d_in[0];
    const float* emb = (const float*)d_in[1];
    float* out = (float*)d_out;
    int*   wi  = (int*)d_ws;
    float* wf  = (float*)d_ws;
    unsigned* wu = (unsigned*)d_ws;
    double* hn64 = (double*)((float*)d_ws + WS_HN64);
    _Float16* ef = (_Float16*)((float*)d_ws + WS_EF);
    float* embT  = (float*)d_ws + WS_ET;

    k_prep<<<KC / 8, 256, 0, stream>>>(emb, ef, embT, wf + WS_HN, hn64, wu + WS_CNT);
    k_argmin<<<NROWS / 128, 128, 0, stream>>>(x, ef, wf + WS_HN,
                                              wi + WS_IDX, wi + WS_CNT, wi + WS_FLAG);
    k_recheck<<<1024, 256, 0, stream>>>(x, embT, hn64, wi + WS_IDX,
                                        wi + WS_CNT, wi + WS_FLAG);
    k_output<<<NB_OUT, 256, 0, stream>>>(x, emb, wi + WS_IDX, out, wf + WS_PART);
    k_hist<<<64, 256, 0, stream>>>(wi + WS_IDX, wu + WS_HIST, wf + WS_PART,
                                   wu + WS_DONE, out);
}

// Round 7
// 103.713 us; speedup vs baseline: 1.5063x; 1.0583x over previous
//
#include <hip/hip_runtime.h>
#include <math.h>

constexpr int DIM   = 128;
constexpr int KC    = 1024;
constexpr int NROWS = 65536;                 // 16384*512/128
constexpr int XEL   = NROWS * DIM;           // 8388608

// output layout (floats)
constexpr int OUT_Z     = 0;
constexpr int OUT_DIFF  = XEL;               // 8388608
constexpr int OUT_CODES = XEL + 1;           // 8388609
constexpr int OUT_PPL   = XEL + 1 + NROWS;   // 8454145

// ws layout (4-byte units)
constexpr int WS_IDX  = 0;                   // int[NROWS]
constexpr int WS_FLAG = NROWS;               // int[NROWS]
constexpr int WS_CNT  = 2 * NROWS;           // int   (zeroed by k_prep)
constexpr int WS_DONE = WS_CNT + 1;          // u32   (zeroed by k_prep)
constexpr int WS_HIST = WS_DONE + 1;         // u32[KC] (zeroed by k_prep)
constexpr int WS_HN   = WS_HIST + KC;        // float[KC]
constexpr int WS_PART = WS_HN + KC;          // float[2048] diff partials
constexpr int WS_HN64 = WS_PART + 2048;      // double[KC] (2048 words, 8B-aligned)
constexpr int WS_EF   = WS_HN64 + 2 * KC;    // _Float16[KC*DIM] = 65536 words
constexpr int WS_ET   = WS_EF + (KC * DIM / 2); // float[DIM*KC] transposed = 131072 words

constexpr int NB_OUT = 2048;                 // k_output blocks

// single-pass f16 score error std ~5e-3; 0.06 = >10 sigma pairwise margin
constexpr float GAP_THR = 0.06f;

typedef _Float16 f16x8 __attribute__((ext_vector_type(8)));
typedef _Float16 f16x4 __attribute__((ext_vector_type(4)));
typedef float f32x4 __attribute__((ext_vector_type(4)));

// ---- emb -> f16 + transposed fp32 + fp64 half-norms; zero counters/hist ----
__global__ __launch_bounds__(256) void k_prep(
        const float* __restrict__ emb, _Float16* __restrict__ ef,
        float* __restrict__ embT, float* __restrict__ hn,
        double* __restrict__ hn64, unsigned* __restrict__ zbase) {
    __shared__ float ldsT[DIM][9];            // 8 codes transposed, +1 pad col
    const int tid = threadIdx.x;
    if (blockIdx.x == 0)
        for (int i = tid; i < 2 + KC; i += 256) zbase[i] = 0u;   // CNT, DONE, HIST
    const int cc   = tid >> 5;                // 0..7 code within block
    const int code = blockIdx.x * 8 + cc;
    const int jq   = tid & 31;                // float4 index
    float4 v = *(const float4*)(emb + (size_t)code * DIM + jq * 4);
    f16x4 h = { (_Float16)v.x, (_Float16)v.y, (_Float16)v.z, (_Float16)v.w };
    *(f16x4*)(ef + (size_t)code * DIM + jq * 4) = h;
    ldsT[jq * 4 + 0][cc] = v.x;
    ldsT[jq * 4 + 1][cc] = v.y;
    ldsT[jq * 4 + 2][cc] = v.z;
    ldsT[jq * 4 + 3][cc] = v.w;
    double s = (double)v.x * v.x + (double)v.y * v.y
             + (double)v.z * v.z + (double)v.w * v.w;
    #pragma unroll
    for (int m = 1; m < 32; m <<= 1) s += __shfl_xor(s, m);
    if (jq == 0) {
        hn[code]   = (float)(0.5 * s);
        hn64[code] = 0.5 * s;
    }
    __syncthreads();
    #pragma unroll
    for (int i = 0; i < 4; ++i) {
        int idx = i * 256 + tid;
        int j = idx >> 3, c = idx & 7;
        embT[(size_t)j * KC + blockIdx.x * 8 + c] = ldsT[j][c];
    }
}

// ---- main: single-pass f16 MFMA scores, 4 waves x 32 rows, top-2 + argmax ----
__global__ __launch_bounds__(256, 2) void k_argmin(
        const float* __restrict__ x, const _Float16* __restrict__ ef,
        const float* __restrict__ hn, int* __restrict__ idx_out,
        int* __restrict__ flag_cnt, int* __restrict__ flagged) {
    __shared__ _Float16 lds[4096];            // 8 KB: 8 chunks of 1 KB
    const int tid = threadIdx.x;
    const int l = tid & 63, w = tid >> 6;     // 4 waves
    const int lr = l & 15, lg = l >> 4;
    const int r0 = blockIdx.x * 128 + w * 32; // 32 rows per wave

    // A fragments: 32 rows as f16 (2 row-groups x 4 k-tiles), in registers
    f16x8 a[2][4];
    #pragma unroll
    for (int i = 0; i < 2; ++i) {
        const float* xr = x + (size_t)(r0 + i * 16 + lr) * DIM + lg * 8;
        #pragma unroll
        for (int kt = 0; kt < 4; ++kt) {
            float4 v0 = *(const float4*)(xr + kt * 32);
            float4 v1 = *(const float4*)(xr + kt * 32 + 4);
            f16x8 av = { (_Float16)v0.x, (_Float16)v0.y, (_Float16)v0.z, (_Float16)v0.w,
                         (_Float16)v1.x, (_Float16)v1.y, (_Float16)v1.z, (_Float16)v1.w };
            a[i][kt] = av;
        }
    }

    // staging: 8 chunks/tile (c in 0..1, kt in 0..3), wave w stages q=w*2+i
    const _Float16* esrc[2];
    #pragma unroll
    for (int i = 0; i < 2; ++i) {
        int q = w * 2 + i, c = q >> 2, kt = q & 3;
        esrc[i] = ef + (size_t)(c * 16 + lr) * DIM + kt * 32 + lg * 8;
    }
    f16x8 st[2];
    #pragma unroll
    for (int i = 0; i < 2; ++i) st[i] = *(const f16x8*)(esrc[i]);

    float m1[2][4], m2[2][4]; int bi[2][4];
    #pragma unroll
    for (int i = 0; i < 2; ++i)
        #pragma unroll
        for (int rg = 0; rg < 4; ++rg) { m1[i][rg] = -3e38f; m2[i][rg] = -3e38f; bi[i][rg] = 0; }

    for (int t = 0; t < KC / 32; ++t) {
        __syncthreads();                      // prev tile's readers done
        #pragma unroll
        for (int i = 0; i < 2; ++i)
            *(f16x8*)(lds + (w * 2 + i) * 512 + l * 8) = st[i];
        __syncthreads();                      // tile t visible
        if (t < KC / 32 - 1) {
            #pragma unroll
            for (int i = 0; i < 2; ++i) st[i] = *(const f16x8*)(esrc[i] + (t + 1) * 32 * DIM);
        }
        const float h0 = hn[t * 32 + lr], h1 = hn[t * 32 + 16 + lr];
        f32x4 acc[2][2];
        #pragma unroll
        for (int i = 0; i < 2; ++i) {
            acc[i][0] = (f32x4){-h0, -h0, -h0, -h0};
            acc[i][1] = (f32x4){-h1, -h1, -h1, -h1};
        }
        #pragma unroll
        for (int kt = 0; kt < 4; ++kt) {
            f16x8 b0 = *(const f16x8*)(lds + kt * 512 + l * 8);
            f16x8 b1 = *(const f16x8*)(lds + 2048 + kt * 512 + l * 8);
            #pragma unroll
            for (int i = 0; i < 2; ++i) {
                acc[i][0] = __builtin_amdgcn_mfma_f32_16x16x32_f16(a[i][kt], b0, acc[i][0], 0, 0, 0);
                acc[i][1] = __builtin_amdgcn_mfma_f32_16x16x32_f16(a[i][kt], b1, acc[i][1], 0, 0, 0);
            }
        }
        const int c0 = t * 32 + lr, c1 = c0 + 16;
        #pragma unroll
        for (int i = 0; i < 2; ++i)
            #pragma unroll
            for (int rg = 0; rg < 4; ++rg) {
                float v0 = acc[i][0][rg], v1 = acc[i][1][rg];
                bool g0 = v0 > m1[i][rg];
                m2[i][rg] = fmaxf(m2[i][rg], fminf(v0, m1[i][rg]));
                m1[i][rg] = fmaxf(m1[i][rg], v0);
                bi[i][rg] = g0 ? c0 : bi[i][rg];
                bool g1 = v1 > m1[i][rg];
                m2[i][rg] = fmaxf(m2[i][rg], fminf(v1, m1[i][rg]));
                m1[i][rg] = fmaxf(m1[i][rg], v1);
                bi[i][rg] = g1 ? c1 : bi[i][rg];
            }
    }

    // merge top-2 across the 16 lanes sharing each row
    #pragma unroll
    for (int i = 0; i < 2; ++i)
        #pragma unroll
        for (int rg = 0; rg < 4; ++rg) {
            float a1 = m1[i][rg], a2 = m2[i][rg]; int ai = bi[i][rg];
            #pragma unroll
            for (int mask = 1; mask < 16; mask <<= 1) {
                float o1 = __shfl_xor(a1, mask);
                float o2 = __shfl_xor(a2, mask);
                int   oi = __shfl_xor(ai, mask);
                float nm2 = fmaxf(fmaxf(a2, o2), fminf(a1, o1));
                if (o1 > a1 || (o1 == a1 && oi < ai)) { a1 = o1; ai = oi; }
                a2 = nm2;
            }
            if (lr == 0) {
                int row = r0 + i * 16 + lg * 4 + rg;
                idx_out[row] = ai;
                if (a1 - a2 < GAP_THR) {      // near-tie: exact recheck later
                    int p = atomicAdd(flag_cnt, 1);
                    flagged[p] = row;
                }
            }
        }
}

// ---- exact fp64 recheck over transposed codebook: block per flagged row ----
__global__ __launch_bounds__(256) void k_recheck(
        const float* __restrict__ x, const float* __restrict__ embT,
        const double* __restrict__ hn64, int* __restrict__ idx_out,
        const int* __restrict__ flag_cnt, const int* __restrict__ flagged) {
    __shared__ double xd[DIM];
    __shared__ double wv[4];
    __shared__ int    wk[4];
    const int tid = threadIdx.x;
    const int cnt = flag_cnt[0];
    for (int f = blockIdx.x; f < cnt; f += gridDim.x) {
        const int row = flagged[f];
        __syncthreads();                       // xd/wv reuse guard
        if (tid < DIM) xd[tid] = (double)x[(size_t)row * DIM + tid];
        __syncthreads();
        const float* tp = embT + tid;
        double s0 = 0.0, s1 = 0.0, s2 = 0.0, s3 = 0.0;
        #pragma unroll 4
        for (int j = 0; j < DIM; ++j) {
            const float* rp = tp + (size_t)j * KC;
            double xv = xd[j];
            s0 = fma((double)rp[0],   xv, s0);
            s1 = fma((double)rp[256], xv, s1);
            s2 = fma((double)rp[512], xv, s2);
            s3 = fma((double)rp[768], xv, s3);
        }
        double bv = s0 - hn64[tid];       int bk = tid;
        double v1 = s1 - hn64[tid + 256];
        if (v1 > bv) { bv = v1; bk = tid + 256; }
        double v2 = s2 - hn64[tid + 512];
        if (v2 > bv) { bv = v2; bk = tid + 512; }
        double v3 = s3 - hn64[tid + 768];
        if (v3 > bv) { bv = v3; bk = tid + 768; }
        #pragma unroll
        for (int m = 1; m < 64; m <<= 1) {
            double ov = __shfl_xor(bv, m);
            int    ok = __shfl_xor(bk, m);
            if (ov > bv || (ov == bv && ok < bk)) { bv = ov; bk = ok; }
        }
        const int w = tid >> 6;
        if ((tid & 63) == 0) { wv[w] = bv; wk[w] = bk; }
        __syncthreads();
        if (tid == 0) {
            double fv = wv[0]; int fk = wk[0];
            #pragma unroll
            for (int i = 1; i < 4; ++i)
                if (wv[i] > fv || (wv[i] == fv && wk[i] < fk)) { fv = wv[i]; fk = wk[i]; }
            idx_out[row] = fk;
        }
    }
}

// ---- z, codes, diff partials (no global atomics) ----
__global__ __launch_bounds__(256) void k_output(
        const float* __restrict__ x, const float* __restrict__ emb,
        const int* __restrict__ idx, float* __restrict__ out,
        float* __restrict__ part) {
    const int tid = threadIdx.x;
    float d = 0.f;
    #pragma unroll
    for (int it = 0; it < 4; ++it) {
        int i = blockIdx.x * 256 + tid + it * (NB_OUT * 256);
        int e0 = i * 4;
        int row = e0 >> 7;
        int col = e0 & (DIM - 1);
        int k = idx[row];
        float4 xv = *(const float4*)(x + e0);
        float4 qv = *(const float4*)(emb + (size_t)k * DIM + col);
        float dx = qv.x - xv.x, dy = qv.y - xv.y, dz = qv.z - xv.z, dw = qv.w - xv.w;
        float4 z;
        z.x = xv.x + dx; z.y = xv.y + dy; z.z = xv.z + dz; z.w = xv.w + dw;
        *(float4*)(out + OUT_Z + e0) = z;
        d += dx*dx + dy*dy + dz*dz + dw*dw;
        if (col == 0) out[OUT_CODES + row] = (float)k;
    }
    for (int off = 32; off; off >>= 1) d += __shfl_down(d, off);
    __shared__ float red[4];
    int lane = tid & 63, w = tid >> 6;
    if (lane == 0) red[w] = d;
    __syncthreads();
    if (tid == 0) part[blockIdx.x] = (red[0] + red[1]) + (red[2] + red[3]);
}

// ---- histogram (64 blocks) + finalize in last-done block ----
__global__ __launch_bounds__(256) void k_hist(
        const int* __restrict__ idx, unsigned* __restrict__ ghist,
        const float* __restrict__ part, unsigned* __restrict__ done,
        float* __restrict__ out) {
    __shared__ unsigned hist[KC];
    __shared__ double sh[256];
    __shared__ unsigned rank_sh;
    const int tid = threadIdx.x;
    #pragma unroll
    for (int i = 0; i < KC / 256; ++i) hist[i * 256 + tid] = 0u;
    __syncthreads();
    const int base = blockIdx.x * (NROWS / 64);
    #pragma unroll
    for (int it = 0; it < NROWS / 64 / 256; ++it)
        atomicAdd(&hist[idx[base + it * 256 + tid]], 1u);
    __syncthreads();
    #pragma unroll
    for (int i = 0; i < KC / 256; ++i) {
        unsigned c = hist[i * 256 + tid];
        if (c) atomicAdd(&ghist[i * 256 + tid], c);
    }
    __syncthreads();                          // all this block's merges complete
    if (tid == 0) { __threadfence(); rank_sh = atomicAdd(done, 1u); }
    __syncthreads();
    if (rank_sh != 63) return;
    // last block: diff mean + perplexity
    double s = 0.0;
    #pragma unroll
    for (int it = 0; it < 2048 / 256; ++it) s += (double)part[it * 256 + tid];
    sh[tid] = s;
    __syncthreads();
    for (int st = 128; st; st >>= 1) {
        if (tid < st) sh[tid] += sh[tid + st];
        __syncthreads();
    }
    double diff = sh[0] * (1.0 / (double)XEL);
    double lp = 0.0;
    #pragma unroll
    for (int i = 0; i < KC / 256; ++i) {
        unsigned c = atomicAdd(&ghist[i * 256 + tid], 0u);   // coherent read
        double p = (double)c * (1.0 / (double)NROWS);
        lp += p * log(p + 1e-5);
    }
    __syncthreads();
    sh[tid] = lp;
    __syncthreads();
    for (int st = 128; st; st >>= 1) {
        if (tid < st) sh[tid] += sh[tid + st];
        __syncthreads();
    }
    if (tid == 0) {
        out[OUT_DIFF] = (float)diff;
        out[OUT_PPL]  = (float)(-sh[0]);
    }
}

extern "C" void kernel_launch(void* const* d_in, const int* in_sizes, int n_in,
                              void* d_out, int out_size, void* d_ws, size_t ws_size,
                              hipStream_t stream) {
    const float* x   = (const float*)d_in[0];
    const float* emb = (const float*)d_in[1];
    float* out = (float*)d_out;
    int*   wi  = (int*)d_ws;
    float* wf  = (float*)d_ws;
    unsigned* wu = (unsigned*)d_ws;
    double* hn64 = (double*)((float*)d_ws + WS_HN64);
    _Float16* ef = (_Float16*)((float*)d_ws + WS_EF);
    float* embT  = (float*)d_ws + WS_ET;

    k_prep<<<KC / 8, 256, 0, stream>>>(emb, ef, embT, wf + WS_HN, hn64, wu + WS_CNT);
    k_argmin<<<NROWS / 128, 256, 0, stream>>>(x, ef, wf + WS_HN,
                                              wi + WS_IDX, wi + WS_CNT, wi + WS_FLAG);
    k_recheck<<<1024, 256, 0, stream>>>(x, embT, hn64, wi + WS_IDX,
                                        wi + WS_CNT, wi + WS_FLAG);
    k_output<<<NB_OUT, 256, 0, stream>>>(x, emb, wi + WS_IDX, out, wf + WS_PART);
    k_hist<<<64, 256, 0, stream>>>(wi + WS_IDX, wu + WS_HIST, wf + WS_PART,
                                   wu + WS_DONE, out);
}

// Round 8
// 98.710 us; speedup vs baseline: 1.5826x; 1.0507x over previous
//
#include <hip/hip_runtime.h>
#include <math.h>

constexpr int DIM   = 128;
constexpr int KC    = 1024;
constexpr int NROWS = 65536;                 // 16384*512/128
constexpr int XEL   = NROWS * DIM;           // 8388608

// output layout (floats)
constexpr int OUT_Z     = 0;
constexpr int OUT_DIFF  = XEL;               // 8388608
constexpr int OUT_CODES = XEL + 1;           // 8388609
constexpr int OUT_PPL   = XEL + 1 + NROWS;   // 8454145

// ws layout (4-byte units)
constexpr int WS_IDX  = 0;                   // int[NROWS]
constexpr int WS_FLAG = NROWS;               // int[NROWS]
constexpr int WS_CNT  = 2 * NROWS;           // int   (zeroed by k_prep)
constexpr int WS_DONE = WS_CNT + 1;          // u32   (zeroed by k_prep)
constexpr int WS_HIST = WS_DONE + 1;         // u32[KC] (zeroed by k_prep)
constexpr int WS_HN   = WS_HIST + KC;        // float[KC]
constexpr int WS_PART = WS_HN + KC;          // float[2048] diff partials
constexpr int WS_HN64 = WS_PART + 2048;      // double[KC] (2048 words, 8B-aligned)
constexpr int WS_EF   = WS_HN64 + 2 * KC;    // _Float16[KC*DIM] = 65536 words
constexpr int WS_ET   = WS_EF + (KC * DIM / 2); // float[DIM*KC] transposed = 131072 words

constexpr int NB_OUT = 2048;                 // k_output blocks

// single-pass f16 score error std ~5e-3; 0.06 = >10 sigma pairwise margin
constexpr float GAP_THR = 0.06f;

typedef _Float16 f16x8 __attribute__((ext_vector_type(8)));
typedef _Float16 f16x4 __attribute__((ext_vector_type(4)));
typedef float f32x4 __attribute__((ext_vector_type(4)));

// ---- emb -> f16 + transposed fp32 + fp64 half-norms; zero counters/hist ----
__global__ __launch_bounds__(256) void k_prep(
        const float* __restrict__ emb, _Float16* __restrict__ ef,
        float* __restrict__ embT, float* __restrict__ hn,
        double* __restrict__ hn64, unsigned* __restrict__ zbase) {
    __shared__ float ldsT[DIM][9];            // 8 codes transposed, +1 pad col
    const int tid = threadIdx.x;
    if (blockIdx.x == 0)
        for (int i = tid; i < 2 + KC; i += 256) zbase[i] = 0u;   // CNT, DONE, HIST
    const int cc   = tid >> 5;                // 0..7 code within block
    const int code = blockIdx.x * 8 + cc;
    const int jq   = tid & 31;                // float4 index
    float4 v = *(const float4*)(emb + (size_t)code * DIM + jq * 4);
    f16x4 h = { (_Float16)v.x, (_Float16)v.y, (_Float16)v.z, (_Float16)v.w };
    *(f16x4*)(ef + (size_t)code * DIM + jq * 4) = h;
    ldsT[jq * 4 + 0][cc] = v.x;
    ldsT[jq * 4 + 1][cc] = v.y;
    ldsT[jq * 4 + 2][cc] = v.z;
    ldsT[jq * 4 + 3][cc] = v.w;
    double s = (double)v.x * v.x + (double)v.y * v.y
             + (double)v.z * v.z + (double)v.w * v.w;
    #pragma unroll
    for (int m = 1; m < 32; m <<= 1) s += __shfl_xor(s, m);
    if (jq == 0) {
        hn[code]   = (float)(0.5 * s);
        hn64[code] = 0.5 * s;
    }
    __syncthreads();
    #pragma unroll
    for (int i = 0; i < 4; ++i) {
        int idx = i * 256 + tid;
        int j = idx >> 3, c = idx & 7;
        embT[(size_t)j * KC + blockIdx.x * 8 + c] = ldsT[j][c];
    }
}

// ---- main: f16 MFMA scores, double-buffered LDS via global_load_lds ----
// 4 waves x 32 rows; 64-code tiles; single barrier per tile.
__global__ __launch_bounds__(256, 2) void k_argmin(
        const float* __restrict__ x, const _Float16* __restrict__ ef,
        const float* __restrict__ hn, int* __restrict__ idx_out,
        int* __restrict__ flag_cnt, int* __restrict__ flagged) {
    __shared__ _Float16 bt[2][8192];          // 2 x 16KB double buffer
    __shared__ float hn_lds[KC];
    const int tid = threadIdx.x;
    const int l = tid & 63, w = tid >> 6;     // 4 waves
    const int lr = l & 15, lg = l >> 4;
    const int r0 = blockIdx.x * 128 + w * 32; // 32 rows per wave

    // stage hn into LDS once
    #pragma unroll
    for (int i = 0; i < 4; ++i) hn_lds[i * 256 + tid] = hn[i * 256 + tid];

    // A fragments: 32 rows as f16 (2 row-groups x 4 k-tiles), in registers
    f16x8 a[2][4];
    #pragma unroll
    for (int i = 0; i < 2; ++i) {
        const float* xr = x + (size_t)(r0 + i * 16 + lr) * DIM + lg * 8;
        #pragma unroll
        for (int kt = 0; kt < 4; ++kt) {
            float4 v0 = *(const float4*)(xr + kt * 32);
            float4 v1 = *(const float4*)(xr + kt * 32 + 4);
            f16x8 av = { (_Float16)v0.x, (_Float16)v0.y, (_Float16)v0.z, (_Float16)v0.w,
                         (_Float16)v1.x, (_Float16)v1.y, (_Float16)v1.z, (_Float16)v1.w };
            a[i][kt] = av;
        }
    }

    // wave w owns chunks q=w*4+i -> codes c=w (16 codes), dims kt=i.
    // LDS dest: wave-uniform chunk base; HW writes base + lane*16B.
    // Global src per lane: code (w*16+lr), dims i*32 + lg*8.
    const _Float16* gsrc[4];
    #pragma unroll
    for (int i = 0; i < 4; ++i)
        gsrc[i] = ef + (size_t)(w * 16 + lr) * DIM + i * 32 + lg * 8;

    #define ISSUE_TILE(t, buf)                                                   \
        {                                                                        \
            _Pragma("unroll")                                                    \
            for (int i_ = 0; i_ < 4; ++i_) {                                     \
                const _Float16* g_ = gsrc[i_] + (size_t)(t) * 64 * DIM;          \
                __builtin_amdgcn_global_load_lds(                                \
                    (const __attribute__((address_space(1))) unsigned*)g_,       \
                    (__attribute__((address_space(3))) unsigned*)                \
                        &bt[buf][(w * 4 + i_) * 512],                            \
                    16, 0, 0);                                                   \
            }                                                                    \
        }

    ISSUE_TILE(0, 0)
    asm volatile("s_waitcnt vmcnt(0)");
    __syncthreads();                          // tile 0 + hn_lds visible

    float m1[2][4], m2[2][4]; int bi[2][4];
    #pragma unroll
    for (int i = 0; i < 2; ++i)
        #pragma unroll
        for (int rg = 0; rg < 4; ++rg) { m1[i][rg] = -3e38f; m2[i][rg] = -3e38f; bi[i][rg] = 0; }

    for (int t = 0; t < KC / 64; ++t) {
        const int buf = t & 1;
        if (t < KC / 64 - 1) ISSUE_TILE(t + 1, buf ^ 1)
        float hnv[4];
        #pragma unroll
        for (int c = 0; c < 4; ++c) hnv[c] = hn_lds[t * 64 + c * 16 + lr];
        f32x4 acc[2][4] = {};                 // 8 independent 4-deep MFMA chains
        __builtin_amdgcn_s_setprio(1);
        #pragma unroll
        for (int kt = 0; kt < 4; ++kt) {
            f16x8 b[4];
            #pragma unroll
            for (int c = 0; c < 4; ++c)
                b[c] = *(const f16x8*)(&bt[buf][(c * 4 + kt) * 512 + l * 8]);
            #pragma unroll
            for (int i = 0; i < 2; ++i)
                #pragma unroll
                for (int c = 0; c < 4; ++c)
                    acc[i][c] = __builtin_amdgcn_mfma_f32_16x16x32_f16(a[i][kt], b[c], acc[i][c], 0, 0, 0);
        }
        __builtin_amdgcn_s_setprio(0);
        #pragma unroll
        for (int i = 0; i < 2; ++i)
            #pragma unroll
            for (int c = 0; c < 4; ++c) {
                const int cc = t * 64 + c * 16 + lr;
                #pragma unroll
                for (int rg = 0; rg < 4; ++rg) {
                    float v = acc[i][c][rg] - hnv[c];
                    bool g = v > m1[i][rg];
                    // m1>=m2 invariant -> median(v,m1,m2) == new second-best
                    m2[i][rg] = fmaxf(fminf(v, m1[i][rg]), m2[i][rg]);
                    m1[i][rg] = fmaxf(m1[i][rg], v);
                    bi[i][rg] = g ? cc : bi[i][rg];
                }
            }
        asm volatile("s_waitcnt vmcnt(0)");   // next-tile loads landed
        __syncthreads();                      // all waves done with bt[buf]
    }
    #undef ISSUE_TILE

    // merge top-2 across the 16 lanes sharing each row
    #pragma unroll
    for (int i = 0; i < 2; ++i)
        #pragma unroll
        for (int rg = 0; rg < 4; ++rg) {
            float a1 = m1[i][rg], a2 = m2[i][rg]; int ai = bi[i][rg];
            #pragma unroll
            for (int mask = 1; mask < 16; mask <<= 1) {
                float o1 = __shfl_xor(a1, mask);
                float o2 = __shfl_xor(a2, mask);
                int   oi = __shfl_xor(ai, mask);
                float nm2 = fmaxf(fmaxf(a2, o2), fminf(a1, o1));
                if (o1 > a1 || (o1 == a1 && oi < ai)) { a1 = o1; ai = oi; }
                a2 = nm2;
            }
            if (lr == 0) {
                int row = r0 + i * 16 + lg * 4 + rg;
                idx_out[row] = ai;
                if (a1 - a2 < GAP_THR) {      // near-tie: exact recheck later
                    int p = atomicAdd(flag_cnt, 1);
                    flagged[p] = row;
                }
            }
        }
}

// ---- exact fp64 recheck over transposed codebook: block per flagged row ----
__global__ __launch_bounds__(256) void k_recheck(
        const float* __restrict__ x, const float* __restrict__ embT,
        const double* __restrict__ hn64, int* __restrict__ idx_out,
        const int* __restrict__ flag_cnt, const int* __restrict__ flagged) {
    __shared__ double xd[DIM];
    __shared__ double wv[4];
    __shared__ int    wk[4];
    const int tid = threadIdx.x;
    const int cnt = flag_cnt[0];
    for (int f = blockIdx.x; f < cnt; f += gridDim.x) {
        const int row = flagged[f];
        __syncthreads();                       // xd/wv reuse guard
        if (tid < DIM) xd[tid] = (double)x[(size_t)row * DIM + tid];
        __syncthreads();
        const float* tp = embT + tid;
        double s0 = 0.0, s1 = 0.0, s2 = 0.0, s3 = 0.0;
        #pragma unroll 4
        for (int j = 0; j < DIM; ++j) {
            const float* rp = tp + (size_t)j * KC;
            double xv = xd[j];
            s0 = fma((double)rp[0],   xv, s0);
            s1 = fma((double)rp[256], xv, s1);
            s2 = fma((double)rp[512], xv, s2);
            s3 = fma((double)rp[768], xv, s3);
        }
        double bv = s0 - hn64[tid];       int bk = tid;
        double v1 = s1 - hn64[tid + 256];
        if (v1 > bv) { bv = v1; bk = tid + 256; }
        double v2 = s2 - hn64[tid + 512];
        if (v2 > bv) { bv = v2; bk = tid + 512; }
        double v3 = s3 - hn64[tid + 768];
        if (v3 > bv) { bv = v3; bk = tid + 768; }
        #pragma unroll
        for (int m = 1; m < 64; m <<= 1) {
            double ov = __shfl_xor(bv, m);
            int    ok = __shfl_xor(bk, m);
            if (ov > bv || (ov == bv && ok < bk)) { bv = ov; bk = ok; }
        }
        const int w = tid >> 6;
        if ((tid & 63) == 0) { wv[w] = bv; wk[w] = bk; }
        __syncthreads();
        if (tid == 0) {
            double fv = wv[0]; int fk = wk[0];
            #pragma unroll
            for (int i = 1; i < 4; ++i)
                if (wv[i] > fv || (wv[i] == fv && wk[i] < fk)) { fv = wv[i]; fk = wk[i]; }
            idx_out[row] = fk;
        }
    }
}

// ---- z, codes, diff partials (no global atomics) ----
__global__ __launch_bounds__(256) void k_output(
        const float* __restrict__ x, const float* __restrict__ emb,
        const int* __restrict__ idx, float* __restrict__ out,
        float* __restrict__ part) {
    const int tid = threadIdx.x;
    float d = 0.f;
    #pragma unroll
    for (int it = 0; it < 4; ++it) {
        int i = blockIdx.x * 256 + tid + it * (NB_OUT * 256);
        int e0 = i * 4;
        int row = e0 >> 7;
        int col = e0 & (DIM - 1);
        int k = idx[row];
        float4 xv = *(const float4*)(x + e0);
        float4 qv = *(const float4*)(emb + (size_t)k * DIM + col);
        float dx = qv.x - xv.x, dy = qv.y - xv.y, dz = qv.z - xv.z, dw = qv.w - xv.w;
        float4 z;
        z.x = xv.x + dx; z.y = xv.y + dy; z.z = xv.z + dz; z.w = xv.w + dw;
        *(float4*)(out + OUT_Z + e0) = z;
        d += dx*dx + dy*dy + dz*dz + dw*dw;
        if (col == 0) out[OUT_CODES + row] = (float)k;
    }
    for (int off = 32; off; off >>= 1) d += __shfl_down(d, off);
    __shared__ float red[4];
    int lane = tid & 63, w = tid >> 6;
    if (lane == 0) red[w] = d;
    __syncthreads();
    if (tid == 0) part[blockIdx.x] = (red[0] + red[1]) + (red[2] + red[3]);
}

// ---- histogram (64 blocks) + finalize in last-done block ----
__global__ __launch_bounds__(256) void k_hist(
        const int* __restrict__ idx, unsigned* __restrict__ ghist,
        const float* __restrict__ part, unsigned* __restrict__ done,
        float* __restrict__ out) {
    __shared__ unsigned hist[KC];
    __shared__ double sh[256];
    __shared__ unsigned rank_sh;
    const int tid = threadIdx.x;
    #pragma unroll
    for (int i = 0; i < KC / 256; ++i) hist[i * 256 + tid] = 0u;
    __syncthreads();
    const int base = blockIdx.x * (NROWS / 64);
    #pragma unroll
    for (int it = 0; it < NROWS / 64 / 256; ++it)
        atomicAdd(&hist[idx[base + it * 256 + tid]], 1u);
    __syncthreads();
    #pragma unroll
    for (int i = 0; i < KC / 256; ++i) {
        unsigned c = hist[i * 256 + tid];
        if (c) atomicAdd(&ghist[i * 256 + tid], c);
    }
    __syncthreads();                          // all this block's merges complete
    if (tid == 0) { __threadfence(); rank_sh = atomicAdd(done, 1u); }
    __syncthreads();
    if (rank_sh != 63) return;
    // last block: diff mean + perplexity
    double s = 0.0;
    #pragma unroll
    for (int it = 0; it < 2048 / 256; ++it) s += (double)part[it * 256 + tid];
    sh[tid] = s;
    __syncthreads();
    for (int st = 128; st; st >>= 1) {
        if (tid < st) sh[tid] += sh[tid + st];
        __syncthreads();
    }
    double diff = sh[0] * (1.0 / (double)XEL);
    double lp = 0.0;
    #pragma unroll
    for (int i = 0; i < KC / 256; ++i) {
        unsigned c = atomicAdd(&ghist[i * 256 + tid], 0u);   // coherent read
        double p = (double)c * (1.0 / (double)NROWS);
        lp += p * log(p + 1e-5);
    }
    __syncthreads();
    sh[tid] = lp;
    __syncthreads();
    for (int st = 128; st; st >>= 1) {
        if (tid < st) sh[tid] += sh[tid + st];
        __syncthreads();
    }
    if (tid == 0) {
        out[OUT_DIFF] = (float)diff;
        out[OUT_PPL]  = (float)(-sh[0]);
    }
}

extern "C" void kernel_launch(void* const* d_in, const int* in_sizes, int n_in,
                              void* d_out, int out_size, void* d_ws, size_t ws_size,
                              hipStream_t stream) {
    const float* x   = (const float*)d_in[0];
    const float* emb = (const float*)d_in[1];
    float* out = (float*)d_out;
    int*   wi  = (int*)d_ws;
    float* wf  = (float*)d_ws;
    unsigned* wu = (unsigned*)d_ws;
    double* hn64 = (double*)((float*)d_ws + WS_HN64);
    _Float16* ef = (_Float16*)((float*)d_ws + WS_EF);
    float* embT  = (float*)d_ws + WS_ET;

    k_prep<<<KC / 8, 256, 0, stream>>>(emb, ef, embT, wf + WS_HN, hn64, wu + WS_CNT);
    k_argmin<<<NROWS / 128, 256, 0, stream>>>(x, ef, wf + WS_HN,
                                              wi + WS_IDX, wi + WS_CNT, wi + WS_FLAG);
    k_recheck<<<1024, 256, 0, stream>>>(x, embT, hn64, wi + WS_IDX,
                                        wi + WS_CNT, wi + WS_FLAG);
    k_output<<<NB_OUT, 256, 0, stream>>>(x, emb, wi + WS_IDX, out, wf + WS_PART);
    k_hist<<<64, 256, 0, stream>>>(wi + WS_IDX, wu + WS_HIST, wf + WS_PART,
                                   wu + WS_DONE, out);
}